// Round 13
// baseline (260.664 us; speedup 1.0000x reference)
//
#include <hip/hip_runtime.h>
#include <hip/hip_bf16.h>
#include <math.h>

// Dims (match reference)
#define NL_    2
#define LDIM   48
#define CDIM   16
#define BDIM   8
#define HDIM   64
#define PI_F   3.14159265358979323846f

// e_edge is an exact function of (species_s, species_r, d); tabulate.
#define GRID_D     2048
#define RC_F       2.0f
#define INV_STEP   ((float)GRID_D / RC_F)
#define TBL_STRIDE (GRID_D + 1)
#define NTAB       (4 * TBL_STRIDE)
#define TBL_BYTES  ((size_t)(NTAB + 4) * sizeof(float))

#define NREP 8                       // XCDs on MI355X (learn_hip m09)
// s_getreg_b32 hwreg(HW_REG_XCC_ID=20, offset=0, size=32): ((32-1)<<11)|(0<<6)|20
#define XCC_GETREG_IMM 63508

__device__ __forceinline__ float silu_f(float v) {
    float e = __expf(-v);
    return v * __builtin_amdgcn_rcpf(1.0f + e);
}
__device__ __forceinline__ float rlane(float v, int k) {
    return __uint_as_float(__builtin_amdgcn_readlane(__float_as_uint(v), k));
}

// ================= K1: fused build(table) + pack(pos4) + zero(replicas) ===========
#define PTS   2
#define TPB_B 64
#define B_BUILD ((NTAB + 4 + PTS - 1) / PTS)   // 4100
#define B_PACK  512
#define B_ZERO  512

__device__ void build_role(int bid,
    const float* __restrict__ W1, const float* __restrict__ b1,
    const float* __restrict__ W2, const float* __restrict__ b2,
    const float* __restrict__ Wv,
    const float* __restrict__ Wm1, const float* __restrict__ bm1,
    const float* __restrict__ Wm2, const float* __restrict__ bm2,
    const float* __restrict__ Wg, const float* __restrict__ Wn,
    const float* __restrict__ Wout, float* __restrict__ tbl)
{
    const int j    = threadIdx.x;
    const int base = bid * PTS;

    float a1[PTS], xv[PTS], pv[PTS], cutv[PTS];

    // stage 1: feat @ W1 + b1, silu (width 64)
    {
        float b1j  = b1[j];
        float w1r0 = W1[0*HDIM + j], w1r1 = W1[1*HDIM + j];
        float w1r2 = W1[2*HDIM + j], w1r3 = W1[3*HDIM + j];
        float w1b[BDIM];
        #pragma unroll
        for (int t = 0; t < BDIM; ++t) w1b[t] = W1[(4 + t)*HDIM + j];

        #pragma unroll
        for (int b = 0; b < PTS; ++b) {
            int gid = base + b;
            int g2  = gid < (NTAB + 4) ? gid : 0;
            int combo; float d;
            if (g2 < NTAB) { combo = g2 / TBL_STRIDE; d = (float)(g2 - combo*TBL_STRIDE) * (RC_F/(float)GRID_D); }
            else           { combo = g2 - NTAB;       d = 0.0f; }
            float inv_de = 1.0f / (d + 1e-9f);
            float tt  = fminf(d * 0.5f, 1.0f);
            cutv[b] = 0.5f * (__cosf(PI_F * tt) + 1.0f);
            float s1, c1; __sincosf(PI_F * d * 0.5f, &s1, &c1);

            float acc = b1j + ((combo >> 1) ? w1r1 : w1r0) + ((combo & 1) ? w1r3 : w1r2);
            float sn_1 = 0.0f, sn = s1;
            #pragma unroll
            for (int t = 0; t < BDIM; ++t) {
                acc = fmaf(sn * inv_de, w1b[t], acc);
                float s2 = 2.0f * c1 * sn - sn_1; sn_1 = sn; sn = s2;
            }
            a1[b] = silu_f(acc);
        }
    }

    // stage 2: @ W2 + b2, * cut (64 -> 48)
    {
        float b2j = (j < LDIM) ? b2[j] : 0.0f;
        float w[HDIM];
        #pragma unroll
        for (int k = 0; k < HDIM; ++k) w[k] = (j < LDIM) ? W2[k*LDIM + j] : 0.0f;
        #pragma unroll
        for (int b = 0; b < PTS; ++b) {
            float ac0 = b2j, ac1 = 0.0f;
            #pragma unroll
            for (int k = 0; k < HDIM; k += 2) {
                ac0 = fmaf(rlane(a1[b], k),     w[k],     ac0);
                ac1 = fmaf(rlane(a1[b], k + 1), w[k + 1], ac1);
            }
            xv[b] = (ac0 + ac1) * cutv[b];
        }
    }

    // p = x @ Wv (48 -> 16)
    {
        float w[LDIM];
        #pragma unroll
        for (int k = 0; k < LDIM; ++k) w[k] = (j < CDIM) ? Wv[k*CDIM + j] : 0.0f;
        #pragma unroll
        for (int b = 0; b < PTS; ++b) {
            float ac0 = 0.0f, ac1 = 0.0f;
            #pragma unroll
            for (int k = 0; k < LDIM; k += 2) {
                ac0 = fmaf(rlane(xv[b], k),     w[k],     ac0);
                ac1 = fmaf(rlane(xv[b], k + 1), w[k + 1], ac1);
            }
            pv[b] = ac0 + ac1;
        }
    }

    // Allegro layers
    #pragma unroll
    for (int l = 0; l < NL_; ++l) {
        {
            float bj = bm1[l*HDIM + j];
            float w[HDIM];
            #pragma unroll
            for (int k = 0; k < HDIM; ++k) w[k] = Wm1[l*(LDIM+CDIM)*HDIM + k*HDIM + j];
            #pragma unroll
            for (int b = 0; b < PTS; ++b) {
                int gid = base + b;
                float uu = ((gid < (NTAB+4) ? gid : 0) < NTAB) ? 1.0f : 0.0f;
                float invb = uu * pv[b] * pv[b];
                float ac0 = bj, ac1 = 0.0f;
                #pragma unroll
                for (int k = 0; k < LDIM; k += 2) {
                    ac0 = fmaf(rlane(xv[b], k),     w[k],     ac0);
                    ac1 = fmaf(rlane(xv[b], k + 1), w[k + 1], ac1);
                }
                #pragma unroll
                for (int k = LDIM; k < LDIM + CDIM; k += 2) {
                    ac0 = fmaf(rlane(invb, k - LDIM),     w[k],     ac0);
                    ac1 = fmaf(rlane(invb, k - LDIM + 1), w[k + 1], ac1);
                }
                a1[b] = silu_f(ac0 + ac1);
            }
        }
        {
            float bj = (j < LDIM) ? bm2[l*LDIM + j] : 0.0f;
            float w[HDIM];
            #pragma unroll
            for (int k = 0; k < HDIM; ++k) w[k] = (j < LDIM) ? Wm2[l*HDIM*LDIM + k*LDIM + j] : 0.0f;
            #pragma unroll
            for (int b = 0; b < PTS; ++b) {
                float ac0 = bj, ac1 = 0.0f;
                #pragma unroll
                for (int k = 0; k < HDIM; k += 2) {
                    ac0 = fmaf(rlane(a1[b], k),     w[k],     ac0);
                    ac1 = fmaf(rlane(a1[b], k + 1), w[k + 1], ac1);
                }
                xv[b] = (xv[b] + ac0 + ac1) * cutv[b];
            }
        }
        {
            float w[LDIM];
            #pragma unroll
            for (int k = 0; k < LDIM; ++k) {
                float v = 0.0f;
                if (j < CDIM)            v = Wg[l*LDIM*CDIM + k*CDIM + j];
                else if (j < 2*CDIM)     v = Wn[l*LDIM*CDIM + k*CDIM + (j - CDIM)];
                w[k] = v;
            }
            #pragma unroll
            for (int b = 0; b < PTS; ++b) {
                float ac0 = 0.0f, ac1 = 0.0f;
                #pragma unroll
                for (int k = 0; k < LDIM; k += 2) {
                    ac0 = fmaf(rlane(xv[b], k),     w[k],     ac0);
                    ac1 = fmaf(rlane(xv[b], k + 1), w[k + 1], ac1);
                }
                float acc = ac0 + ac1;
                float nvs = __shfl(acc, (threadIdx.x & 63) + 16, 64);
                pv[b] = fmaf(pv[b], acc, nvs);
            }
        }
    }

    // readout
    {
        float wo = (j < LDIM) ? Wout[j] : 0.0f;
        #pragma unroll
        for (int b = 0; b < PTS; ++b) {
            float v = xv[b] * wo;
            #pragma unroll
            for (int off = 1; off < 64; off <<= 1) v += __shfl_xor(v, off, 64);
            int gid = base + b;
            if (j == 0 && gid < NTAB + 4) tbl[gid] = v * cutv[b] * (1.0f / 3.0f);
        }
    }
}

__launch_bounds__(TPB_B)
__global__ void k1_fused(
    const float* __restrict__ pos, const int* __restrict__ species,
    const float* __restrict__ W1, const float* __restrict__ b1,
    const float* __restrict__ W2, const float* __restrict__ b2,
    const float* __restrict__ Wv,
    const float* __restrict__ Wm1, const float* __restrict__ bm1,
    const float* __restrict__ Wm2, const float* __restrict__ bm2,
    const float* __restrict__ Wg, const float* __restrict__ Wn,
    const float* __restrict__ Wout,
    float* __restrict__ tbl, float4* __restrict__ pos4,
    float4* __restrict__ rep4, int N)
{
    int bid = blockIdx.x;
    if (bid < B_BUILD) {
        build_role(bid, W1, b1, W2, b2, Wv, Wm1, bm1, Wm2, bm2, Wg, Wn, Wout, tbl);
    } else if (bid < B_BUILD + B_PACK) {
        int t0 = (bid - B_BUILD) * TPB_B + threadIdx.x;
        for (int i = t0; i < N; i += B_PACK * TPB_B)
            pos4[i] = make_float4(pos[3*i+0], pos[3*i+1], pos[3*i+2], (float)species[i]);
    } else {
        int t0 = (bid - B_BUILD - B_PACK) * TPB_B + threadIdx.x;
        int nf4 = 2 * N;   // 8*N floats = 2*N float4
        float4 z = make_float4(0.f, 0.f, 0.f, 0.f);
        for (int i = t0; i < nf4; i += B_ZERO * TPB_B) rep4[i] = z;
    }
}

// ================= K2: edge pass, XCD-local atomics to replicas ====================
#define TPB_E 256
__device__ __forceinline__ float edge_eval(const float4& ps, const float4& pr,
                                           const float* __restrict__ tbl) {
    float rx = pr.x - ps.x, ry = pr.y - ps.y, rz = pr.z - ps.z;
    float d  = sqrtf(rx*rx + ry*ry + rz*rz);
    int combo = (int)ps.w * 2 + (int)pr.w;
    if (d > 0.0f) {
        float t = fminf(d * INV_STEP, (float)GRID_D);
        int i0 = (int)t;
        i0 = i0 < (GRID_D - 1) ? i0 : (GRID_D - 1);
        float f = t - (float)i0;
        const float* tb = tbl + combo * TBL_STRIDE + i0;
        float a = tb[0], b = tb[1];
        return fmaf(f, b - a, a);
    }
    return tbl[NTAB + combo];
}

__launch_bounds__(TPB_E)
__global__ void edge_scatter_v3(
    const float4* __restrict__ pos4,
    const int* __restrict__ senders, const int* __restrict__ receivers,
    const float* __restrict__ tbl, float* __restrict__ rep, int N, int E)
{
    // Per-XCD replica: every atomic to rep[xcc*N + r] is issued only from XCD xcc
    // -> XCD-local L2 RMW (workgroup-scope: no device-scope EA escalation).
    int xcc = __builtin_amdgcn_s_getreg(XCC_GETREG_IMM) & (NREP - 1);
    float* myrep = rep + (size_t)xcc * N;

    int t  = blockIdx.x * TPB_E + threadIdx.x;
    int e0 = t * 2;
    if (e0 >= E) return;
    if (e0 + 1 < E) {
        int2 s2 = *reinterpret_cast<const int2*>(senders + e0);
        int2 r2 = *reinterpret_cast<const int2*>(receivers + e0);
        float eo0 = edge_eval(pos4[s2.x], pos4[r2.x], tbl);
        float eo1 = edge_eval(pos4[s2.y], pos4[r2.y], tbl);
        __hip_atomic_fetch_add(&myrep[r2.x], eo0, __ATOMIC_RELAXED, __HIP_MEMORY_SCOPE_WORKGROUP);
        __hip_atomic_fetch_add(&myrep[r2.y], eo1, __ATOMIC_RELAXED, __HIP_MEMORY_SCOPE_WORKGROUP);
    } else {
        int s = senders[e0], r = receivers[e0];
        float eo = edge_eval(pos4[s], pos4[r], tbl);
        __hip_atomic_fetch_add(&myrep[r], eo, __ATOMIC_RELAXED, __HIP_MEMORY_SCOPE_WORKGROUP);
    }
}

// ================= K3: reduce replicas -> out =====================================
__launch_bounds__(256)
__global__ void reduce_rep(const float* __restrict__ rep, float* __restrict__ out, int N) {
    int n = blockIdx.x * 256 + threadIdx.x;
    if (n >= N) return;
    float s = 0.0f;
    #pragma unroll
    for (int x = 0; x < NREP; ++x) s += rep[(size_t)x * N + n];
    out[n] = s;
}

// ================= fallback: R8-validated path (device-scope atomics) ==============
__launch_bounds__(TPB_B)
__global__ void build_table_v2(
    const float* __restrict__ W1, const float* __restrict__ b1,
    const float* __restrict__ W2, const float* __restrict__ b2,
    const float* __restrict__ Wv,
    const float* __restrict__ Wm1, const float* __restrict__ bm1,
    const float* __restrict__ Wm2, const float* __restrict__ bm2,
    const float* __restrict__ Wg, const float* __restrict__ Wn,
    const float* __restrict__ Wout, float* __restrict__ tbl)
{
    build_role(blockIdx.x, W1, b1, W2, b2, Wv, Wm1, bm1, Wm2, bm2, Wg, Wn, Wout, tbl);
}

__global__ void pack_pos4(const float* __restrict__ pos, const int* __restrict__ species,
                          float4* __restrict__ pos4, int N) {
    int i = blockIdx.x * blockDim.x + threadIdx.x;
    if (i < N) pos4[i] = make_float4(pos[3*i+0], pos[3*i+1], pos[3*i+2], (float)species[i]);
}

__launch_bounds__(TPB_E)
__global__ void edge_scatter_v2(
    const float4* __restrict__ pos4,
    const int* __restrict__ senders, const int* __restrict__ receivers,
    const float* __restrict__ tbl, float* __restrict__ out, int E)
{
    int t  = blockIdx.x * TPB_E + threadIdx.x;
    int e0 = t * 2;
    if (e0 >= E) return;
    if (e0 + 1 < E) {
        int2 s2 = *reinterpret_cast<const int2*>(senders + e0);
        int2 r2 = *reinterpret_cast<const int2*>(receivers + e0);
        float eo0 = edge_eval(pos4[s2.x], pos4[r2.x], tbl);
        float eo1 = edge_eval(pos4[s2.y], pos4[r2.y], tbl);
        atomicAdd(&out[r2.x], eo0);
        atomicAdd(&out[r2.y], eo1);
    } else {
        int s = senders[e0], r = receivers[e0];
        float eo = edge_eval(pos4[s], pos4[r], tbl);
        atomicAdd(&out[r], eo);
    }
}

extern "C" void kernel_launch(void* const* d_in, const int* in_sizes, int n_in,
                              void* d_out, int out_size, void* d_ws, size_t ws_size,
                              hipStream_t stream) {
    const float* pos      = (const float*)d_in[0];
    const int*   species  = (const int*)  d_in[1];
    const int*   senders  = (const int*)  d_in[2];
    const int*   receivers= (const int*)  d_in[3];
    const float* W1   = (const float*)d_in[4];
    const float* b1   = (const float*)d_in[5];
    const float* W2   = (const float*)d_in[6];
    const float* b2   = (const float*)d_in[7];
    const float* Wv   = (const float*)d_in[8];
    const float* Wm1  = (const float*)d_in[9];
    const float* bm1  = (const float*)d_in[10];
    const float* Wm2  = (const float*)d_in[11];
    const float* bm2  = (const float*)d_in[12];
    const float* Wg   = (const float*)d_in[13];
    const float* Wn   = (const float*)d_in[14];
    const float* Wout = (const float*)d_in[15];

    float* out = (float*)d_out;
    int N = out_size;
    int E = in_sizes[2];

    size_t pos4_bytes = (size_t)N * sizeof(float4);
    size_t rep_bytes  = (size_t)NREP * N * sizeof(float);
    size_t need_v3    = pos4_bytes + TBL_BYTES + rep_bytes;
    size_t need_v2    = pos4_bytes + TBL_BYTES;

    if (ws_size >= need_v3) {
        float4* pos4 = (float4*)d_ws;
        float*  tbl  = (float*)((char*)d_ws + pos4_bytes);
        float*  rep  = (float*)((char*)d_ws + pos4_bytes + TBL_BYTES);
        k1_fused<<<B_BUILD + B_PACK + B_ZERO, TPB_B, 0, stream>>>(
            pos, species, W1, b1, W2, b2, Wv, Wm1, bm1, Wm2, bm2, Wg, Wn, Wout,
            tbl, pos4, (float4*)rep, N);
        int nthr = (E + 1) / 2;
        edge_scatter_v3<<<(nthr + TPB_E - 1) / TPB_E, TPB_E, 0, stream>>>(
            pos4, senders, receivers, tbl, rep, N, E);
        reduce_rep<<<(N + 255) / 256, 256, 0, stream>>>(rep, out, N);
    } else if (ws_size >= need_v2) {
        hipMemsetAsync(out, 0, (size_t)N * sizeof(float), stream);
        float4* pos4 = (float4*)d_ws;
        float*  tbl  = (float*)((char*)d_ws + pos4_bytes);
        pack_pos4<<<(N + 255) / 256, 256, 0, stream>>>(pos, species, pos4, N);
        build_table_v2<<<B_BUILD, TPB_B, 0, stream>>>(
            W1, b1, W2, b2, Wv, Wm1, bm1, Wm2, bm2, Wg, Wn, Wout, tbl);
        int nthr = (E + 1) / 2;
        edge_scatter_v2<<<(nthr + TPB_E - 1) / TPB_E, TPB_E, 0, stream>>>(
            pos4, senders, receivers, tbl, out, E);
    }
    // (problem sizes guarantee ws >= need_v2 in this harness; R8 ran the v2 path)
}

// Round 14
// 248.400 us; speedup vs baseline: 1.0494x; 1.0494x over previous
//
#include <hip/hip_runtime.h>
#include <hip/hip_bf16.h>
#include <math.h>

// Dims (match reference)
#define NL_    2
#define LDIM   48
#define CDIM   16
#define BDIM   8
#define HDIM   64
#define PI_F   3.14159265358979323846f

// e_edge is an exact function of (species_s, species_r, d); tabulate.
#define GRID_D     2048
#define RC_F       2.0f
#define INV_STEP   ((float)GRID_D / RC_F)
#define TBL_STRIDE (GRID_D + 1)
#define NTAB       (4 * TBL_STRIDE)
#define TBL_BYTES  ((size_t)(NTAB + 4) * sizeof(float))

#define NREP 8                       // XCDs on MI355X (learn_hip m09)
// s_getreg_b32 hwreg(HW_REG_XCC_ID=20, offset=0, size=32): ((32-1)<<11)|(0<<6)|20
#define XCC_GETREG_IMM 63508

__device__ __forceinline__ float silu_f(float v) {
    float e = __expf(-v);
    return v * __builtin_amdgcn_rcpf(1.0f + e);
}
__device__ __forceinline__ float rlane(float v, int k) {
    return __uint_as_float(__builtin_amdgcn_readlane(__float_as_uint(v), k));
}

// ================= K1: fused build(table) + pack(pos4) + zero(replicas) ===========
// Build: ONE point per wave (8200 waves -> 8/SIMD grid TLP), chunked weight loads
// (w[8] live, not w[64]) so VGPR <= 64 -> 8 waves/SIMD VGPR-side too.
#define TPB_B 64
#define B_BUILD (NTAB + 4)     // 8200
#define B_PACK  512
#define B_ZERO  512
#define CHUNK   8

__device__ void build_role(int gid,
    const float* __restrict__ W1, const float* __restrict__ b1,
    const float* __restrict__ W2, const float* __restrict__ b2,
    const float* __restrict__ Wv,
    const float* __restrict__ Wm1, const float* __restrict__ bm1,
    const float* __restrict__ Wm2, const float* __restrict__ bm2,
    const float* __restrict__ Wg, const float* __restrict__ Wn,
    const float* __restrict__ Wout, float* __restrict__ tbl)
{
    const int j = threadIdx.x;

    // decode point
    int combo; float d, uu;
    if (gid < NTAB) {
        combo = gid / TBL_STRIDE;
        d  = (float)(gid - combo * TBL_STRIDE) * (RC_F / (float)GRID_D);
        uu = 1.0f;
    } else {
        combo = gid - NTAB; d = 0.0f; uu = 0.0f;
    }
    float inv_de = 1.0f / (d + 1e-9f);
    float tt  = fminf(d * 0.5f, 1.0f);
    float cutv = 0.5f * (__cosf(PI_F * tt) + 1.0f);
    float s1, c1; __sincosf(PI_F * d * 0.5f, &s1, &c1);

    // ---- stage 1: feat @ W1 + b1, silu (width 64); 13 small preloads ----
    float a1;
    {
        float acc = b1[j]
                  + ((combo >> 1) ? W1[1*HDIM + j] : W1[0*HDIM + j])
                  + ((combo & 1)  ? W1[3*HDIM + j] : W1[2*HDIM + j]);
        float sn_1 = 0.0f, sn = s1;
        #pragma unroll
        for (int t = 0; t < BDIM; ++t) {
            acc = fmaf(sn * inv_de, W1[(4 + t)*HDIM + j], acc);
            float s2 = 2.0f * c1 * sn - sn_1; sn_1 = sn; sn = s2;
        }
        a1 = silu_f(acc);
    }

    // ---- stage 2: @ W2 + b2, * cut (64 -> 48), chunked ----
    float xv;
    {
        float ac0 = (j < LDIM) ? b2[j] : 0.0f, ac1 = 0.0f;
        #pragma unroll 1
        for (int kc = 0; kc < HDIM; kc += CHUNK) {
            float w[CHUNK];
            #pragma unroll
            for (int u = 0; u < CHUNK; ++u) w[u] = (j < LDIM) ? W2[(kc+u)*LDIM + j] : 0.0f;
            #pragma unroll
            for (int u = 0; u < CHUNK; u += 2) {
                ac0 = fmaf(rlane(a1, kc + u),     w[u],     ac0);
                ac1 = fmaf(rlane(a1, kc + u + 1), w[u + 1], ac1);
            }
        }
        xv = (ac0 + ac1) * cutv;
    }

    // ---- p = x @ Wv (48 -> 16), chunked ----
    float pv;
    {
        float ac0 = 0.0f, ac1 = 0.0f;
        #pragma unroll 1
        for (int kc = 0; kc < LDIM; kc += CHUNK) {
            float w[CHUNK];
            #pragma unroll
            for (int u = 0; u < CHUNK; ++u) w[u] = (j < CDIM) ? Wv[(kc+u)*CDIM + j] : 0.0f;
            #pragma unroll
            for (int u = 0; u < CHUNK; u += 2) {
                ac0 = fmaf(rlane(xv, kc + u),     w[u],     ac0);
                ac1 = fmaf(rlane(xv, kc + u + 1), w[u + 1], ac1);
            }
        }
        pv = ac0 + ac1;
    }

    // ---- Allegro layers ----
    #pragma unroll
    for (int l = 0; l < NL_; ++l) {
        // mlp1: concat(x, inv) @ Wm1 + bm1, silu (64 -> 64)
        {
            const float* wm1 = Wm1 + l*(LDIM+CDIM)*HDIM;
            float invb = uu * pv * pv;            // valid at lanes < CDIM
            float ac0 = bm1[l*HDIM + j], ac1 = 0.0f;
            #pragma unroll 1
            for (int kc = 0; kc < LDIM; kc += CHUNK) {
                float w[CHUNK];
                #pragma unroll
                for (int u = 0; u < CHUNK; ++u) w[u] = wm1[(kc+u)*HDIM + j];
                #pragma unroll
                for (int u = 0; u < CHUNK; u += 2) {
                    ac0 = fmaf(rlane(xv, kc + u),     w[u],     ac0);
                    ac1 = fmaf(rlane(xv, kc + u + 1), w[u + 1], ac1);
                }
            }
            {   // inv block: k = 48..63
                float w[CDIM];
                #pragma unroll
                for (int u = 0; u < CDIM; ++u) w[u] = wm1[(LDIM+u)*HDIM + j];
                #pragma unroll
                for (int u = 0; u < CDIM; u += 2) {
                    ac0 = fmaf(rlane(invb, u),     w[u],     ac0);
                    ac1 = fmaf(rlane(invb, u + 1), w[u + 1], ac1);
                }
            }
            a1 = silu_f(ac0 + ac1);
        }
        // mlp2: @ Wm2 + bm2; x = (x + dx) * cut (64 -> 48)
        {
            const float* wm2 = Wm2 + l*HDIM*LDIM;
            float ac0 = (j < LDIM) ? bm2[l*LDIM + j] : 0.0f, ac1 = 0.0f;
            #pragma unroll 1
            for (int kc = 0; kc < HDIM; kc += CHUNK) {
                float w[CHUNK];
                #pragma unroll
                for (int u = 0; u < CHUNK; ++u) w[u] = (j < LDIM) ? wm2[(kc+u)*LDIM + j] : 0.0f;
                #pragma unroll
                for (int u = 0; u < CHUNK; u += 2) {
                    ac0 = fmaf(rlane(a1, kc + u),     w[u],     ac0);
                    ac1 = fmaf(rlane(a1, kc + u + 1), w[u + 1], ac1);
                }
            }
            xv = (xv + ac0 + ac1) * cutv;
        }
        // gate & new in one pass: lanes 0..15 -> g, 16..31 -> nv (48 -> 16 x2)
        {
            const float* wg = Wg + l*LDIM*CDIM;
            const float* wn = Wn + l*LDIM*CDIM;
            float ac0 = 0.0f, ac1 = 0.0f;
            #pragma unroll 1
            for (int kc = 0; kc < LDIM; kc += CHUNK) {
                float w[CHUNK];
                #pragma unroll
                for (int u = 0; u < CHUNK; ++u) {
                    float v = 0.0f;
                    if (j < CDIM)        v = wg[(kc+u)*CDIM + j];
                    else if (j < 2*CDIM) v = wn[(kc+u)*CDIM + (j - CDIM)];
                    w[u] = v;
                }
                #pragma unroll
                for (int u = 0; u < CHUNK; u += 2) {
                    ac0 = fmaf(rlane(xv, kc + u),     w[u],     ac0);
                    ac1 = fmaf(rlane(xv, kc + u + 1), w[u + 1], ac1);
                }
            }
            float acc = ac0 + ac1;
            float nvs = __shfl(acc, (threadIdx.x & 63) + 16, 64); // lanes<16 pull nv
            pv = fmaf(pv, acc, nvs);                              // valid at lanes<16
        }
    }

    // ---- readout: eo = (x . Wout) * cut / 3 ----
    {
        float v = ((j < LDIM) ? Wout[j] : 0.0f) * xv;
        #pragma unroll
        for (int off = 1; off < 64; off <<= 1) v += __shfl_xor(v, off, 64);
        if (j == 0) tbl[gid] = v * cutv * (1.0f / 3.0f);
    }
}

__launch_bounds__(TPB_B, 8)
__global__ void k1_fused(
    const float* __restrict__ pos, const int* __restrict__ species,
    const float* __restrict__ W1, const float* __restrict__ b1,
    const float* __restrict__ W2, const float* __restrict__ b2,
    const float* __restrict__ Wv,
    const float* __restrict__ Wm1, const float* __restrict__ bm1,
    const float* __restrict__ Wm2, const float* __restrict__ bm2,
    const float* __restrict__ Wg, const float* __restrict__ Wn,
    const float* __restrict__ Wout,
    float* __restrict__ tbl, float4* __restrict__ pos4,
    float4* __restrict__ rep4, int N)
{
    int bid = blockIdx.x;
    if (bid < B_BUILD) {
        build_role(bid, W1, b1, W2, b2, Wv, Wm1, bm1, Wm2, bm2, Wg, Wn, Wout, tbl);
    } else if (bid < B_BUILD + B_PACK) {
        int t0 = (bid - B_BUILD) * TPB_B + threadIdx.x;
        for (int i = t0; i < N; i += B_PACK * TPB_B)
            pos4[i] = make_float4(pos[3*i+0], pos[3*i+1], pos[3*i+2], (float)species[i]);
    } else {
        int t0 = (bid - B_BUILD - B_PACK) * TPB_B + threadIdx.x;
        int nf4 = 2 * N;   // 8*N floats = 2*N float4
        float4 z = make_float4(0.f, 0.f, 0.f, 0.f);
        for (int i = t0; i < nf4; i += B_ZERO * TPB_B) rep4[i] = z;
    }
}

// ================= K2: edge pass, XCD-local atomics to replicas ====================
#define TPB_E 256
__device__ __forceinline__ float edge_eval(const float4& ps, const float4& pr,
                                           const float* __restrict__ tbl) {
    float rx = pr.x - ps.x, ry = pr.y - ps.y, rz = pr.z - ps.z;
    float d  = sqrtf(rx*rx + ry*ry + rz*rz);
    int combo = (int)ps.w * 2 + (int)pr.w;
    if (d > 0.0f) {
        float t = fminf(d * INV_STEP, (float)GRID_D);
        int i0 = (int)t;
        i0 = i0 < (GRID_D - 1) ? i0 : (GRID_D - 1);
        float f = t - (float)i0;
        const float* tb = tbl + combo * TBL_STRIDE + i0;
        float a = tb[0], b = tb[1];
        return fmaf(f, b - a, a);
    }
    return tbl[NTAB + combo];
}

__launch_bounds__(TPB_E)
__global__ void edge_scatter_v3(
    const float4* __restrict__ pos4,
    const int* __restrict__ senders, const int* __restrict__ receivers,
    const float* __restrict__ tbl, float* __restrict__ rep, int N, int E)
{
    // Per-XCD replica: every atomic to rep[xcc*N + r] is issued only from XCD xcc
    // -> XCD-local L2 RMW (workgroup-scope: no device-scope EA escalation).
    int xcc = __builtin_amdgcn_s_getreg(XCC_GETREG_IMM) & (NREP - 1);
    float* myrep = rep + (size_t)xcc * N;

    int t  = blockIdx.x * TPB_E + threadIdx.x;
    int e0 = t * 2;
    if (e0 >= E) return;
    if (e0 + 1 < E) {
        int2 s2 = *reinterpret_cast<const int2*>(senders + e0);
        int2 r2 = *reinterpret_cast<const int2*>(receivers + e0);
        float eo0 = edge_eval(pos4[s2.x], pos4[r2.x], tbl);
        float eo1 = edge_eval(pos4[s2.y], pos4[r2.y], tbl);
        __hip_atomic_fetch_add(&myrep[r2.x], eo0, __ATOMIC_RELAXED, __HIP_MEMORY_SCOPE_WORKGROUP);
        __hip_atomic_fetch_add(&myrep[r2.y], eo1, __ATOMIC_RELAXED, __HIP_MEMORY_SCOPE_WORKGROUP);
    } else {
        int s = senders[e0], r = receivers[e0];
        float eo = edge_eval(pos4[s], pos4[r], tbl);
        __hip_atomic_fetch_add(&myrep[r], eo, __ATOMIC_RELAXED, __HIP_MEMORY_SCOPE_WORKGROUP);
    }
}

// ================= K3: reduce replicas -> out =====================================
__launch_bounds__(256)
__global__ void reduce_rep(const float* __restrict__ rep, float* __restrict__ out, int N) {
    int n = blockIdx.x * 256 + threadIdx.x;
    if (n >= N) return;
    float s = 0.0f;
    #pragma unroll
    for (int x = 0; x < NREP; ++x) s += rep[(size_t)x * N + n];
    out[n] = s;
}

// ================= fallback: R8-validated path (device-scope atomics) ==============
__launch_bounds__(TPB_B, 8)
__global__ void build_table_v2(
    const float* __restrict__ W1, const float* __restrict__ b1,
    const float* __restrict__ W2, const float* __restrict__ b2,
    const float* __restrict__ Wv,
    const float* __restrict__ Wm1, const float* __restrict__ bm1,
    const float* __restrict__ Wm2, const float* __restrict__ bm2,
    const float* __restrict__ Wg, const float* __restrict__ Wn,
    const float* __restrict__ Wout, float* __restrict__ tbl)
{
    build_role(blockIdx.x, W1, b1, W2, b2, Wv, Wm1, bm1, Wm2, bm2, Wg, Wn, Wout, tbl);
}

__global__ void pack_pos4(const float* __restrict__ pos, const int* __restrict__ species,
                          float4* __restrict__ pos4, int N) {
    int i = blockIdx.x * blockDim.x + threadIdx.x;
    if (i < N) pos4[i] = make_float4(pos[3*i+0], pos[3*i+1], pos[3*i+2], (float)species[i]);
}

__launch_bounds__(TPB_E)
__global__ void edge_scatter_v2(
    const float4* __restrict__ pos4,
    const int* __restrict__ senders, const int* __restrict__ receivers,
    const float* __restrict__ tbl, float* __restrict__ out, int E)
{
    int t  = blockIdx.x * TPB_E + threadIdx.x;
    int e0 = t * 2;
    if (e0 >= E) return;
    if (e0 + 1 < E) {
        int2 s2 = *reinterpret_cast<const int2*>(senders + e0);
        int2 r2 = *reinterpret_cast<const int2*>(receivers + e0);
        float eo0 = edge_eval(pos4[s2.x], pos4[r2.x], tbl);
        float eo1 = edge_eval(pos4[s2.y], pos4[r2.y], tbl);
        atomicAdd(&out[r2.x], eo0);
        atomicAdd(&out[r2.y], eo1);
    } else {
        int s = senders[e0], r = receivers[e0];
        float eo = edge_eval(pos4[s], pos4[r], tbl);
        atomicAdd(&out[r], eo);
    }
}

extern "C" void kernel_launch(void* const* d_in, const int* in_sizes, int n_in,
                              void* d_out, int out_size, void* d_ws, size_t ws_size,
                              hipStream_t stream) {
    const float* pos      = (const float*)d_in[0];
    const int*   species  = (const int*)  d_in[1];
    const int*   senders  = (const int*)  d_in[2];
    const int*   receivers= (const int*)  d_in[3];
    const float* W1   = (const float*)d_in[4];
    const float* b1   = (const float*)d_in[5];
    const float* W2   = (const float*)d_in[6];
    const float* b2   = (const float*)d_in[7];
    const float* Wv   = (const float*)d_in[8];
    const float* Wm1  = (const float*)d_in[9];
    const float* bm1  = (const float*)d_in[10];
    const float* Wm2  = (const float*)d_in[11];
    const float* bm2  = (const float*)d_in[12];
    const float* Wg   = (const float*)d_in[13];
    const float* Wn   = (const float*)d_in[14];
    const float* Wout = (const float*)d_in[15];

    float* out = (float*)d_out;
    int N = out_size;
    int E = in_sizes[2];

    size_t pos4_bytes = (size_t)N * sizeof(float4);
    size_t rep_bytes  = (size_t)NREP * N * sizeof(float);
    size_t need_v3    = pos4_bytes + TBL_BYTES + rep_bytes;
    size_t need_v2    = pos4_bytes + TBL_BYTES;

    if (ws_size >= need_v3) {
        float4* pos4 = (float4*)d_ws;
        float*  tbl  = (float*)((char*)d_ws + pos4_bytes);
        float*  rep  = (float*)((char*)d_ws + pos4_bytes + TBL_BYTES);
        k1_fused<<<B_BUILD + B_PACK + B_ZERO, TPB_B, 0, stream>>>(
            pos, species, W1, b1, W2, b2, Wv, Wm1, bm1, Wm2, bm2, Wg, Wn, Wout,
            tbl, pos4, (float4*)rep, N);
        int nthr = (E + 1) / 2;
        edge_scatter_v3<<<(nthr + TPB_E - 1) / TPB_E, TPB_E, 0, stream>>>(
            pos4, senders, receivers, tbl, rep, N, E);
        reduce_rep<<<(N + 255) / 256, 256, 0, stream>>>(rep, out, N);
    } else if (ws_size >= need_v2) {
        hipMemsetAsync(out, 0, (size_t)N * sizeof(float), stream);
        float4* pos4 = (float4*)d_ws;
        float*  tbl  = (float*)((char*)d_ws + pos4_bytes);
        pack_pos4<<<(N + 255) / 256, 256, 0, stream>>>(pos, species, pos4, N);
        build_table_v2<<<B_BUILD, TPB_B, 0, stream>>>(
            W1, b1, W2, b2, Wv, Wm1, bm1, Wm2, bm2, Wg, Wn, Wout, tbl);
        int nthr = (E + 1) / 2;
        edge_scatter_v2<<<(nthr + TPB_E - 1) / TPB_E, TPB_E, 0, stream>>>(
            pos4, senders, receivers, tbl, out, E);
    }
    // (problem sizes guarantee ws >= need_v2 in this harness)
}